// Round 8
// baseline (396.463 us; speedup 1.0000x reference)
//
#include <hip/hip_runtime.h>

#define DIM   1024
#define HID   512
#define NEXP  16
#define TOPK  4
#define SLOTS 5
#define PITCH 72     // 64 + 8 bf16 pad: row stride 36 words -> cheap bank alias (m136)
#define TPE   16     // 128-row tiles per expert

typedef unsigned short u16;
typedef unsigned int   u32;
typedef short bf16x8 __attribute__((ext_vector_type(8)));
typedef float f32x4  __attribute__((ext_vector_type(4)));

__device__ __forceinline__ float bf2f(u16 u) {
    union { u32 i; float f; } v; v.i = ((u32)u) << 16; return v.f;
}
__device__ __forceinline__ u16 f2bf(float f) {
    union { float f; u32 i; } v; v.f = f;
    u32 lsb = (v.i >> 16) & 1u;
    v.i += 0x7fffu + lsb;              // round-to-nearest-even
    return (u16)(v.i >> 16);
}
__device__ __forceinline__ uint4 pack8(float4 a, float4 b) {
    uint4 r;
    r.x = (u32)f2bf(a.x) | ((u32)f2bf(a.y) << 16);
    r.y = (u32)f2bf(a.z) | ((u32)f2bf(a.w) << 16);
    r.z = (u32)f2bf(b.x) | ((u32)f2bf(b.y) << 16);
    r.w = (u32)f2bf(b.z) | ((u32)f2bf(b.w) << 16);
    return r;
}

// segment boundaries (8-elem chunks) in the contiguous bf16 dst buffer:
// [w1 | sw1 | w3 | sw3 | w2 | sw2 | x]  -> W1c/W3c/W2c each get expert 16 = shared
#define CW ((size_t)NEXP * HID * DIM / 8)   // 1,048,576
#define CS ((size_t)HID * DIM / 8)          //    65,536
#define SEG_B0 (CW)
#define SEG_B1 (SEG_B0 + CS)
#define SEG_B2 (SEG_B1 + CW)
#define SEG_B3 (SEG_B2 + CS)
#define SEG_B4 (SEG_B3 + CW)
#define SEG_B5 (SEG_B4 + CS)                // 3,342,336 chunks (weights only)

// ------------------------------------------------------------------- prep ---
// blocks [0, T): router (4 waves x 4 experts; logits bit-identical to serial).
// blocks [T, T+nCvt): fp32->bf16 of all weights + x, 2 chunks (64 B) / thread.
__global__ __launch_bounds__(256) void moe_prep(
    const float* __restrict__ x,    const float* __restrict__ gate,
    const float* __restrict__ w1,   const float* __restrict__ w3,
    const float* __restrict__ w2,   const float* __restrict__ sw1,
    const float* __restrict__ sw3,  const float* __restrict__ sw2,
    u16* __restrict__ dst,
    int* __restrict__ counts, u32* __restrict__ pairs,
    float* __restrict__ wslot, int T)
{
    const int blk = blockIdx.x;
    const int tid = threadIdx.x;
    if (blk >= T) {
        // ---- conversion ----
        const size_t base = (size_t)(blk - T) * 512 + tid;
        const size_t totC = SEG_B5 + ((size_t)T << 7);   // + T*DIM/8 x-chunks
#pragma unroll
        for (int h = 0; h < 2; ++h) {
            const size_t c = base + (size_t)h * 256;     // chunk id
            if (c >= totC) break;
            const float* src; size_t loc;
            if      (c < SEG_B0) { src = w1;  loc = c; }
            else if (c < SEG_B1) { src = sw1; loc = c - SEG_B0; }
            else if (c < SEG_B2) { src = w3;  loc = c - SEG_B1; }
            else if (c < SEG_B3) { src = sw3; loc = c - SEG_B2; }
            else if (c < SEG_B4) { src = w2;  loc = c - SEG_B3; }
            else if (c < SEG_B5) { src = sw2; loc = c - SEG_B4; }
            else                 { src = x;   loc = c - SEG_B5; }
            float4 a = ((const float4*)src)[loc * 2];
            float4 b = ((const float4*)src)[loc * 2 + 1];
            ((uint4*)dst)[c] = pack8(a, b);
        }
        return;
    }
    // ---- router: 4 waves, wave wv computes experts 4wv..4wv+3 ----
    const int t    = blk;
    const int lane = tid & 63;
    const int wv   = tid >> 6;
    const float* xrow = x + (size_t)t * DIM;
    float xr[16];
#pragma unroll
    for (int j = 0; j < 16; ++j) xr[j] = xrow[lane + 64 * j];

    __shared__ float slog[NEXP];
#pragma unroll
    for (int i = 0; i < 4; ++i) {
        const int e = wv * 4 + i;
        const float* g = gate + (size_t)e * DIM;
        float s = 0.f;
#pragma unroll
        for (int j = 0; j < 16; ++j) s += xr[j] * g[lane + 64 * j];
#pragma unroll
        for (int off = 32; off > 0; off >>= 1) s += __shfl_xor(s, off);
        if (lane == 0) slog[e] = s;
    }
    __syncthreads();
    if (wv != 0) return;

    float v[NEXP];
#pragma unroll
    for (int e = 0; e < NEXP; ++e) v[e] = slog[e];
    int idx[TOPK]; float lv[TOPK];
#pragma unroll
    for (int r = 0; r < TOPK; ++r) {                 // strict > : lax.top_k ties
        int be = 0; float bv = v[0];
        for (int e = 1; e < NEXP; ++e) { if (v[e] > bv) { bv = v[e]; be = e; } }
        idx[r] = be; lv[r] = bv; v[be] = -3.0e38f;
    }
    float wk[TOPK]; float wsum = 0.f;
#pragma unroll
    for (int r = 0; r < TOPK; ++r) { wk[r] = __expf(lv[r] - lv[0]); wsum += wk[r]; }
#pragma unroll
    for (int r = 0; r < TOPK; ++r) wk[r] /= wsum;

    if (lane < TOPK) {
        int e = idx[lane];
        int slot = atomicAdd(&counts[e], 1);
        if (slot < T) pairs[(size_t)e * T + slot] = ((u32)t << 3) | (u32)lane;
        wslot[t * SLOTS + lane] = wk[lane];
    } else if (lane == TOPK) {
        pairs[(size_t)NEXP * T + t] = ((u32)t << 3) | 4u;   // shared expert
        wslot[t * SLOTS + 4] = 1.0f;
    }
}

// ------------------------------------------------------------------ gemm1 ---
// 128x128x64 tiles (bf16): act = silu(x.W1_e^T) * (x.W3_e^T).
// Dense enumeration (expert fastest). T14 async-STAGE: next K-tile is
// prefetched into registers BEFORE the MFMA cluster, written to LDS after the
// barrier -> global-load latency hides under MFMA (this kernel runs at
// ~1 block/CU, so there is no TLP to hide it otherwise; r7: 7.3% occ, 82us).
__global__ __launch_bounds__(256) void moe_gemm1(
    const u16* __restrict__ xb,
    const u16* __restrict__ w1c, const u16* __restrict__ w3c,
    const u32* __restrict__ pairs, const int* __restrict__ counts,
    u16* __restrict__ act, int T)
{
    const int ytile = blockIdx.y;                    // 0..271
    const int e     = ytile % (NEXP + 1);            // expert fastest
    const int ti    = ytile / (NEXP + 1);            // tile within expert
    const int r0    = ti << 7;
    const int n0    = blockIdx.x * 128;
    const int cnt = (e == NEXP) ? T : min(max(counts[e], 0), T);
    if (r0 >= cnt) return;
    const int nv = min(128, cnt - r0);

    const u16* W1 = w1c + (size_t)e * HID * DIM;
    const u16* W3 = w3c + (size_t)e * HID * DIM;

    __shared__ __align__(16) u16 sA [128 * PITCH];
    __shared__ __align__(16) u16 sB1[128 * PITCH];
    __shared__ __align__(16) u16 sB3[128 * PITCH];
    __shared__ u32 sEnt[128];

    const int tid = threadIdx.x;
    if (tid < 128) {
        u32 ent = (tid < nv) ? pairs[(size_t)e * T + r0 + tid] : 0u;
        u32 tk = ent >> 3, sl = ent & 7u;
        if (tk >= (u32)T) tk = 0;
        if (sl >= SLOTS)  sl = 0;
        sEnt[tid] = (tk << 3) | sl;
    }
    __syncthreads();

    const int ar = tid >> 1;            // staging row 0..127
    const int ac = (tid & 1) * 32;      // 32 elems (4 uint4) per thread
    const u16* xrow  = xb + (size_t)(sEnt[ar] >> 3) * DIM;
    const u16* b1row = W1 + (size_t)(n0 + ar) * DIM;
    const u16* b3row = W3 + (size_t)(n0 + ar) * DIM;

    const int wv   = tid >> 6;
    const int lane = tid & 63;
    const int l15  = lane & 15;
    const int kq   = (lane >> 4) * 8;
    const int m0   = (wv & 1) * 64;     // wave 2x2 grid over 128x128
    const int nc0  = (wv >> 1) * 64;

    f32x4 acc1[4][4], acc3[4][4];
#pragma unroll
    for (int i = 0; i < 4; ++i)
#pragma unroll
        for (int j = 0; j < 4; ++j) { acc1[i][j] = (f32x4){0,0,0,0}; acc3[i][j] = (f32x4){0,0,0,0}; }

    // T14 prologue: load K-tile 0 into registers
    uint4 rA[4], rB1[4], rB3[4];
#pragma unroll
    for (int u = 0; u < 4; ++u) {
        rA [u] = *(const uint4*)&xrow [ac + u*8];
        rB1[u] = *(const uint4*)&b1row[ac + u*8];
        rB3[u] = *(const uint4*)&b3row[ac + u*8];
    }

    for (int kt = 0; kt < DIM; kt += 64) {
        __syncthreads();                 // prev MFMA done reading LDS
#pragma unroll
        for (int u = 0; u < 4; ++u) {    // write-late: regs -> LDS
            *(uint4*)&sA [ar*PITCH + ac + u*8] = rA [u];
            *(uint4*)&sB1[ar*PITCH + ac + u*8] = rB1[u];
            *(uint4*)&sB3[ar*PITCH + ac + u*8] = rB3[u];
        }
        __syncthreads();
        if (kt + 64 < DIM) {             // issue-early: next tile loads
#pragma unroll
            for (int u = 0; u < 4; ++u) {
                rA [u] = *(const uint4*)&xrow [kt + 64 + ac + u*8];
                rB1[u] = *(const uint4*)&b1row[kt + 64 + ac + u*8];
                rB3[u] = *(const uint4*)&b3row[kt + 64 + ac + u*8];
            }
        }
#pragma unroll
        for (int ks = 0; ks < 64; ks += 32) {
            bf16x8 af[4], b1f[4], b3f[4];
#pragma unroll
            for (int mf = 0; mf < 4; ++mf)
                af[mf] = *(const bf16x8*)&sA[(m0 + mf*16 + l15)*PITCH + ks + kq];
#pragma unroll
            for (int nf = 0; nf < 4; ++nf) {
                b1f[nf] = *(const bf16x8*)&sB1[(nc0 + nf*16 + l15)*PITCH + ks + kq];
                b3f[nf] = *(const bf16x8*)&sB3[(nc0 + nf*16 + l15)*PITCH + ks + kq];
            }
#pragma unroll
            for (int mf = 0; mf < 4; ++mf)
#pragma unroll
                for (int nf = 0; nf < 4; ++nf) {
                    acc1[mf][nf] = __builtin_amdgcn_mfma_f32_16x16x32_bf16(af[mf], b1f[nf], acc1[mf][nf], 0, 0, 0);
                    acc3[mf][nf] = __builtin_amdgcn_mfma_f32_16x16x32_bf16(af[mf], b3f[nf], acc3[mf][nf], 0, 0, 0);
                }
        }
    }
    // C/D: col = lane&15, row = (lane>>4)*4 + reg   (m89-verified)
#pragma unroll
    for (int mf = 0; mf < 4; ++mf)
#pragma unroll
    for (int nf = 0; nf < 4; ++nf)
#pragma unroll
    for (int r = 0; r < 4; ++r) {
        int ml = m0 + mf*16 + (lane >> 4)*4 + r;
        if (ml < nv) {
            float h1 = acc1[mf][nf][r], h3 = acc3[mf][nf][r];
            float a = (h1 / (1.f + __expf(-h1))) * h3;       // silu(h1)*h3
            u32 ent = sEnt[ml];
            size_t sidx = (size_t)(ent >> 3) * SLOTS + (ent & 7u);
            act[sidx * HID + n0 + nc0 + nf*16 + l15] = f2bf(a);
        }
    }
}

// ------------------------------------------------------------------ gemm2 ---
// 128x128x64 tiles (bf16), 37 KB LDS. Dense enumeration + T14 async-STAGE.
__global__ __launch_bounds__(256) void moe_gemm2(
    const u16* __restrict__ act, const u16* __restrict__ w2c,
    const u32* __restrict__ pairs, const float* __restrict__ wslot,
    const int* __restrict__ counts,
    u16* __restrict__ eout, float* __restrict__ out, int useEout, int T)
{
    const int ytile = blockIdx.y;                    // 0..271
    const int e     = ytile % (NEXP + 1);            // expert fastest
    const int ti    = ytile / (NEXP + 1);
    const int r0    = ti << 7;
    const int n0    = blockIdx.x * 128;
    const int cnt = (e == NEXP) ? T : min(max(counts[e], 0), T);
    if (r0 >= cnt) return;
    const int nv = min(128, cnt - r0);

    const u16* W2 = w2c + (size_t)e * DIM * HID;

    __shared__ __align__(16) u16 sA[128 * PITCH];
    __shared__ __align__(16) u16 sB[128 * PITCH];
    __shared__ u32 sEnt[128];

    const int tid = threadIdx.x;
    if (tid < 128) {
        u32 ent = (tid < nv) ? pairs[(size_t)e * T + r0 + tid] : 0u;
        u32 tk = ent >> 3, sl = ent & 7u;
        if (tk >= (u32)T) tk = 0;
        if (sl >= SLOTS)  sl = 0;
        sEnt[tid] = (tk << 3) | sl;
    }
    __syncthreads();

    const int ar = tid >> 1;
    const int ac = (tid & 1) * 32;
    const u32 entA = sEnt[ar];
    const u16* arow = act + ((size_t)(entA >> 3) * SLOTS + (entA & 7u)) * HID;
    const u16* brow = W2 + (size_t)(n0 + ar) * HID;

    const int wv   = tid >> 6;
    const int lane = tid & 63;
    const int l15  = lane & 15;
    const int kq   = (lane >> 4) * 8;
    const int m0   = (wv & 1) * 64;     // wave 2x2 grid over 128x128
    const int nc0  = (wv >> 1) * 64;

    f32x4 acc[4][4];
#pragma unroll
    for (int i = 0; i < 4; ++i)
#pragma unroll
        for (int j = 0; j < 4; ++j) acc[i][j] = (f32x4){0,0,0,0};

    // T14 prologue
    uint4 rA[4], rB[4];
#pragma unroll
    for (int u = 0; u < 4; ++u) {
        rA[u] = *(const uint4*)&arow[ac + u*8];
        rB[u] = *(const uint4*)&brow[ac + u*8];
    }

    for (int kt = 0; kt < HID; kt += 64) {
        __syncthreads();
#pragma unroll
        for (int u = 0; u < 4; ++u) {
            *(uint4*)&sA[ar*PITCH + ac + u*8] = rA[u];
            *(uint4*)&sB[ar*PITCH + ac + u*8] = rB[u];
        }
        __syncthreads();
        if (kt + 64 < HID) {
#pragma unroll
            for (int u = 0; u < 4; ++u) {
                rA[u] = *(const uint4*)&arow[kt + 64 + ac + u*8];
                rB[u] = *(const uint4*)&brow[kt + 64 + ac + u*8];
            }
        }
#pragma unroll
        for (int ks = 0; ks < 64; ks += 32) {
            bf16x8 af[4], bf[4];
#pragma unroll
            for (int mf = 0; mf < 4; ++mf)
                af[mf] = *(const bf16x8*)&sA[(m0 + mf*16 + l15)*PITCH + ks + kq];
#pragma unroll
            for (int nf = 0; nf < 4; ++nf)
                bf[nf] = *(const bf16x8*)&sB[(nc0 + nf*16 + l15)*PITCH + ks + kq];
#pragma unroll
            for (int mf = 0; mf < 4; ++mf)
#pragma unroll
                for (int nf = 0; nf < 4; ++nf)
                    acc[mf][nf] = __builtin_amdgcn_mfma_f32_16x16x32_bf16(af[mf], bf[nf], acc[mf][nf], 0, 0, 0);
        }
    }
#pragma unroll
    for (int mf = 0; mf < 4; ++mf)
#pragma unroll
    for (int nf = 0; nf < 4; ++nf)
#pragma unroll
    for (int r = 0; r < 4; ++r) {
        int ml = m0 + mf*16 + (lane >> 4)*4 + r;
        if (ml < nv) {
            u32 ent = sEnt[ml];
            u32 tk = ent >> 3;
            float cw = wslot[tk * SLOTS + (ent & 7u)];
            int col = n0 + nc0 + nf*16 + l15;
            float v = cw * acc[mf][nf][r];
            if (useEout) {
                size_t sidx = (size_t)tk * SLOTS + (ent & 7u);
                eout[sidx * DIM + col] = f2bf(v);
            } else {
                atomicAdd(&out[(size_t)tk * DIM + col], v);
            }
        }
    }
}

// ---------------------------------------------------------------- combine ---
__global__ __launch_bounds__(256) void moe_combine(
    const u16* __restrict__ eout, float* __restrict__ out, int n4)
{
    int i = blockIdx.x * 256 + threadIdx.x;
    if (i >= n4) return;
    int o4 = i * 4;
    int t = o4 >> 10;                   // DIM = 1024
    int col = o4 & 1023;
    float a0 = 0.f, a1 = 0.f, a2 = 0.f, a3 = 0.f;
#pragma unroll
    for (int s = 0; s < SLOTS; ++s) {
        const u16* row = eout + ((size_t)t * SLOTS + s) * DIM + col;
        ushort4 u = *(const ushort4*)row;
        a0 += bf2f(u.x); a1 += bf2f(u.y); a2 += bf2f(u.z); a3 += bf2f(u.w);
    }
    float4* op = (float4*)(out + (size_t)t * DIM + col);
    *op = (float4){a0, a1, a2, a3};
}

// ------------------------------------------------------------------ launch --
extern "C" void kernel_launch(void* const* d_in, const int* in_sizes, int n_in,
                              void* d_out, int out_size, void* d_ws, size_t ws_size,
                              hipStream_t stream)
{
    (void)n_in; (void)out_size;
    const float* x    = (const float*)d_in[0];
    const float* gate = (const float*)d_in[1];
    const float* w1   = (const float*)d_in[2];
    const float* w3   = (const float*)d_in[3];
    const float* w2   = (const float*)d_in[4];
    const float* sw1  = (const float*)d_in[5];
    const float* sw3  = (const float*)d_in[6];
    const float* sw2  = (const float*)d_in[7];
    float* out = (float*)d_out;
    const int T = in_sizes[0] / DIM;     // 2048

    char* w = (char*)d_ws;
    int*  counts = (int*)(w);            // 256 B zeroed each call
    size_t off = 4096;
    u32*   pairs = (u32*)(w + off);  off += (size_t)(NEXP + 1) * T * 4;   // 139 KB
    float* wslot = (float*)(w + off); off += (size_t)T * SLOTS * 4;       //  40 KB
    off = (off + 255) & ~(size_t)255;
    u16*   actb  = (u16*)(w + off);  off += (size_t)T * SLOTS * HID * 2;  // 10.5 MB
    off = (off + 255) & ~(size_t)255;
    u16*   cvtb  = (u16*)(w + off);
    const size_t xChunks = (size_t)T * DIM / 8;
    const size_t cvtChunks = SEG_B5 + xChunks;                            // 3,604,480
    off += cvtChunks * 8 * 2;                                             // 57.7 MB
    off = (off + 255) & ~(size_t)255;
    u16*   eoutb = (u16*)(w + off);
    const size_t needEout = off + (size_t)T * SLOTS * DIM * 2;            // ~89.4 MB

    u16* W1c = cvtb;                       // [17][HID][DIM] (sw1 = expert 16)
    u16* W3c = cvtb + SEG_B1 * 8;
    u16* W2c = cvtb + SEG_B3 * 8;
    u16* xb  = cvtb + SEG_B5 * 8;

    const int useEout = (ws_size >= needEout) ? 1 : 0;   // constant -> graph-safe

    hipMemsetAsync(w, 0, 256, stream);                   // counts
    if (!useEout)
        hipMemsetAsync(out, 0, (size_t)T * DIM * sizeof(float), stream);

    const int nCvt = (int)((cvtChunks + 511) / 512);     // 2 chunks / thread
    moe_prep<<<T + nCvt, 256, 0, stream>>>(
        x, gate, w1, w3, w2, sw1, sw3, sw2, cvtb, counts, pairs, wslot, T);

    moe_gemm1<<<dim3(HID / 128, (NEXP + 1) * TPE), 256, 0, stream>>>(
        xb, W1c, W3c, pairs, counts, actb, T);
    moe_gemm2<<<dim3(DIM / 128, (NEXP + 1) * TPE), 256, 0, stream>>>(
        actb, W2c, pairs, wslot, counts, eoutb, out, useEout, T);
    if (useEout)
        moe_combine<<<(T * DIM / 4 + 255) / 256, 256, 0, stream>>>(
            eoutb, out, T * DIM / 4);
}

// Round 9
// 250.145 us; speedup vs baseline: 1.5849x; 1.5849x over previous
//
#include <hip/hip_runtime.h>

#define DIM   1024
#define HID   512
#define NEXP  16
#define TOPK  4
#define SLOTS 5
#define PITCH 72     // 64 + 8 bf16 pad: row stride 36 words -> cheap bank alias (m136)
#define TPE   16     // 128-row tiles per expert

typedef unsigned short u16;
typedef unsigned int   u32;
typedef short bf16x8 __attribute__((ext_vector_type(8)));
typedef float f32x4  __attribute__((ext_vector_type(4)));
typedef float f32x4v __attribute__((ext_vector_type(4)));
typedef unsigned int u32x4v __attribute__((ext_vector_type(4)));

__device__ __forceinline__ float bf2f(u16 u) {
    union { u32 i; float f; } v; v.i = ((u32)u) << 16; return v.f;
}
__device__ __forceinline__ u16 f2bf(float f) {
    union { float f; u32 i; } v; v.f = f;
    u32 lsb = (v.i >> 16) & 1u;
    v.i += 0x7fffu + lsb;              // round-to-nearest-even
    return (u16)(v.i >> 16);
}
__device__ __forceinline__ uint4 pack8(float4 a, float4 b) {
    uint4 r;
    r.x = (u32)f2bf(a.x) | ((u32)f2bf(a.y) << 16);
    r.y = (u32)f2bf(a.z) | ((u32)f2bf(a.w) << 16);
    r.z = (u32)f2bf(b.x) | ((u32)f2bf(b.y) << 16);
    r.w = (u32)f2bf(b.z) | ((u32)f2bf(b.w) << 16);
    return r;
}
__device__ __forceinline__ u32x4v pack8v(f32x4v a, f32x4v b) {
    u32x4v r;
    r.x = (u32)f2bf(a.x) | ((u32)f2bf(a.y) << 16);
    r.y = (u32)f2bf(a.z) | ((u32)f2bf(a.w) << 16);
    r.z = (u32)f2bf(b.x) | ((u32)f2bf(b.y) << 16);
    r.w = (u32)f2bf(b.z) | ((u32)f2bf(b.w) << 16);
    return r;
}

// segment boundaries (8-elem chunks) in the contiguous bf16 dst buffer:
// [w1 | sw1 | w3 | sw3 | w2 | sw2 | x]  -> W1c/W3c/W2c each get expert 16 = shared
#define CW ((size_t)NEXP * HID * DIM / 8)   // 1,048,576
#define CS ((size_t)HID * DIM / 8)          //    65,536
#define SEG_B0 (CW)
#define SEG_B1 (SEG_B0 + CS)
#define SEG_B2 (SEG_B1 + CW)
#define SEG_B3 (SEG_B2 + CS)
#define SEG_B4 (SEG_B3 + CW)
#define SEG_B5 (SEG_B4 + CS)                // 3,342,336 chunks (weights only)

// ------------------------------------------------------------------- prep ---
// blocks [0, T): router (4 waves x 4 experts; logits bit-identical to serial).
// blocks [T, T+nCvt): fp32->bf16, 2 chunks/thread, NONTEMPORAL loads+stores
// (read-once fp32 sources, write-once bf16 dst: bypass L2 write-allocate so
// the two streams stop thrashing each other — prep has sat at 1.6 TB/s HBM
// with all pipes idle across r0-r7).
__global__ __launch_bounds__(256) void moe_prep(
    const float* __restrict__ x,    const float* __restrict__ gate,
    const float* __restrict__ w1,   const float* __restrict__ w3,
    const float* __restrict__ w2,   const float* __restrict__ sw1,
    const float* __restrict__ sw3,  const float* __restrict__ sw2,
    u16* __restrict__ dst,
    int* __restrict__ counts, u32* __restrict__ pairs,
    float* __restrict__ wslot, int T)
{
    const int blk = blockIdx.x;
    const int tid = threadIdx.x;
    if (blk >= T) {
        // ---- conversion ----
        const size_t base = (size_t)(blk - T) * 512 + tid;
        const size_t totC = SEG_B5 + ((size_t)T << 7);   // + T*DIM/8 x-chunks
#pragma unroll
        for (int h = 0; h < 2; ++h) {
            const size_t c = base + (size_t)h * 256;     // chunk id
            if (c >= totC) break;
            const float* src; size_t loc;
            if      (c < SEG_B0) { src = w1;  loc = c; }
            else if (c < SEG_B1) { src = sw1; loc = c - SEG_B0; }
            else if (c < SEG_B2) { src = w3;  loc = c - SEG_B1; }
            else if (c < SEG_B3) { src = sw3; loc = c - SEG_B2; }
            else if (c < SEG_B4) { src = w2;  loc = c - SEG_B3; }
            else if (c < SEG_B5) { src = sw2; loc = c - SEG_B4; }
            else                 { src = x;   loc = c - SEG_B5; }
            f32x4v a = __builtin_nontemporal_load((const f32x4v*)src + loc * 2);
            f32x4v b = __builtin_nontemporal_load((const f32x4v*)src + loc * 2 + 1);
            __builtin_nontemporal_store(pack8v(a, b), (u32x4v*)dst + c);
        }
        return;
    }
    // ---- router: 4 waves, wave wv computes experts 4wv..4wv+3 ----
    const int t    = blk;
    const int lane = tid & 63;
    const int wv   = tid >> 6;
    const float* xrow = x + (size_t)t * DIM;
    float xr[16];
#pragma unroll
    for (int j = 0; j < 16; ++j) xr[j] = xrow[lane + 64 * j];

    __shared__ float slog[NEXP];
#pragma unroll
    for (int i = 0; i < 4; ++i) {
        const int e = wv * 4 + i;
        const float* g = gate + (size_t)e * DIM;
        float s = 0.f;
#pragma unroll
        for (int j = 0; j < 16; ++j) s += xr[j] * g[lane + 64 * j];
#pragma unroll
        for (int off = 32; off > 0; off >>= 1) s += __shfl_xor(s, off);
        if (lane == 0) slog[e] = s;
    }
    __syncthreads();
    if (wv != 0) return;

    float v[NEXP];
#pragma unroll
    for (int e = 0; e < NEXP; ++e) v[e] = slog[e];
    int idx[TOPK]; float lv[TOPK];
#pragma unroll
    for (int r = 0; r < TOPK; ++r) {                 // strict > : lax.top_k ties
        int be = 0; float bv = v[0];
        for (int e = 1; e < NEXP; ++e) { if (v[e] > bv) { bv = v[e]; be = e; } }
        idx[r] = be; lv[r] = bv; v[be] = -3.0e38f;
    }
    float wk[TOPK]; float wsum = 0.f;
#pragma unroll
    for (int r = 0; r < TOPK; ++r) { wk[r] = __expf(lv[r] - lv[0]); wsum += wk[r]; }
#pragma unroll
    for (int r = 0; r < TOPK; ++r) wk[r] /= wsum;

    if (lane < TOPK) {
        int e = idx[lane];
        int slot = atomicAdd(&counts[e], 1);
        if (slot < T) pairs[(size_t)e * T + slot] = ((u32)t << 3) | (u32)lane;
        wslot[t * SLOTS + lane] = wk[lane];
    } else if (lane == TOPK) {
        pairs[(size_t)NEXP * T + t] = ((u32)t << 3) | 4u;   // shared expert
        wslot[t * SLOTS + 4] = 1.0f;
    }
}

// ------------------------------------------------------------------ gemm1 ---
// r0-proven geometry: 128x64x64 tiles, 37 KB LDS -> 4 blocks/CU, ~740 working
// blocks (~2.9/CU) — TLP hides the 2-phase staging latency (m114). Dense
// modulo enumeration (expert fastest), no builder kernel.
// acc: wave wv owns M rows [wv*32, wv*32+32), all 64 N cols; dual acc1/acc3.
__global__ __launch_bounds__(256) void moe_gemm1(
    const u16* __restrict__ xb,
    const u16* __restrict__ w1c, const u16* __restrict__ w3c,
    const u32* __restrict__ pairs, const int* __restrict__ counts,
    u16* __restrict__ act, int T)
{
    const int ytile = blockIdx.y;                    // 0..271
    const int e     = ytile % (NEXP + 1);            // expert fastest -> dense
    const int ti    = ytile / (NEXP + 1);
    const int r0    = ti << 7;
    const int n0    = blockIdx.x * 64;
    const int cnt = (e == NEXP) ? T : min(max(counts[e], 0), T);
    if (r0 >= cnt) return;
    const int nv = min(128, cnt - r0);

    const u16* W1 = w1c + (size_t)e * HID * DIM;
    const u16* W3 = w3c + (size_t)e * HID * DIM;

    __shared__ __align__(16) u16 sA [128 * PITCH];
    __shared__ __align__(16) u16 sB1[ 64 * PITCH];
    __shared__ __align__(16) u16 sB3[ 64 * PITCH];
    __shared__ u32 sEnt[128];

    const int tid = threadIdx.x;
    if (tid < 128) {
        u32 ent = (tid < nv) ? pairs[(size_t)e * T + r0 + tid] : 0u;
        u32 tk = ent >> 3, sl = ent & 7u;
        if (tk >= (u32)T) tk = 0;
        if (sl >= SLOTS)  sl = 0;
        sEnt[tid] = (tk << 3) | sl;
    }
    __syncthreads();

    const int ar = tid >> 1;            // sA staging row 0..127
    const int ac = (tid & 1) * 32;      // 32 elems (4 uint4) per thread
    const u16* xrow = xb + (size_t)(sEnt[ar] >> 3) * DIM;
    const int br = tid >> 2;            // sB row 0..63
    const int bc = (tid & 3) * 16;      // 16 elems (2 uint4)
    const u16* b1row = W1 + (size_t)(n0 + br) * DIM;
    const u16* b3row = W3 + (size_t)(n0 + br) * DIM;

    const int wv   = tid >> 6;          // wave -> M rows [wv*32, wv*32+32)
    const int lane = tid & 63;
    const int l15  = lane & 15;
    const int kq   = (lane >> 4) * 8;
    const int m0   = wv * 32;

    f32x4 acc1[2][4], acc3[2][4];
#pragma unroll
    for (int i = 0; i < 2; ++i)
#pragma unroll
        for (int j = 0; j < 4; ++j) { acc1[i][j] = (f32x4){0,0,0,0}; acc3[i][j] = (f32x4){0,0,0,0}; }

    for (int kt = 0; kt < DIM; kt += 64) {
        __syncthreads();
        *(uint4*)&sA [ar*PITCH + ac]      = *(const uint4*)&xrow [kt + ac];
        *(uint4*)&sA [ar*PITCH + ac +  8] = *(const uint4*)&xrow [kt + ac +  8];
        *(uint4*)&sA [ar*PITCH + ac + 16] = *(const uint4*)&xrow [kt + ac + 16];
        *(uint4*)&sA [ar*PITCH + ac + 24] = *(const uint4*)&xrow [kt + ac + 24];
        *(uint4*)&sB1[br*PITCH + bc]      = *(const uint4*)&b1row[kt + bc];
        *(uint4*)&sB1[br*PITCH + bc +  8] = *(const uint4*)&b1row[kt + bc + 8];
        *(uint4*)&sB3[br*PITCH + bc]      = *(const uint4*)&b3row[kt + bc];
        *(uint4*)&sB3[br*PITCH + bc +  8] = *(const uint4*)&b3row[kt + bc + 8];
        __syncthreads();
#pragma unroll
        for (int ks = 0; ks < 64; ks += 32) {
            bf16x8 a0 = *(const bf16x8*)&sA[(m0      + l15)*PITCH + ks + kq];
            bf16x8 a1 = *(const bf16x8*)&sA[(m0 + 16 + l15)*PITCH + ks + kq];
#pragma unroll
            for (int nt = 0; nt < 4; ++nt) {
                bf16x8 b1 = *(const bf16x8*)&sB1[(nt*16 + l15)*PITCH + ks + kq];
                bf16x8 b3 = *(const bf16x8*)&sB3[(nt*16 + l15)*PITCH + ks + kq];
                acc1[0][nt] = __builtin_amdgcn_mfma_f32_16x16x32_bf16(a0, b1, acc1[0][nt], 0, 0, 0);
                acc1[1][nt] = __builtin_amdgcn_mfma_f32_16x16x32_bf16(a1, b1, acc1[1][nt], 0, 0, 0);
                acc3[0][nt] = __builtin_amdgcn_mfma_f32_16x16x32_bf16(a0, b3, acc3[0][nt], 0, 0, 0);
                acc3[1][nt] = __builtin_amdgcn_mfma_f32_16x16x32_bf16(a1, b3, acc3[1][nt], 0, 0, 0);
            }
        }
    }
    // C/D: col = lane&15, row = (lane>>4)*4 + reg   (m89-verified)
#pragma unroll
    for (int mf = 0; mf < 2; ++mf)
#pragma unroll
    for (int nt = 0; nt < 4; ++nt)
#pragma unroll
    for (int r = 0; r < 4; ++r) {
        int ml = m0 + mf*16 + (lane >> 4)*4 + r;
        if (ml < nv) {
            float h1 = acc1[mf][nt][r], h3 = acc3[mf][nt][r];
            float a = (h1 / (1.f + __expf(-h1))) * h3;       // silu(h1)*h3
            u32 ent = sEnt[ml];
            size_t sidx = (size_t)(ent >> 3) * SLOTS + (ent & 7u);
            act[sidx * HID + n0 + nt*16 + l15] = f2bf(a);
        }
    }
}

// ------------------------------------------------------------------ gemm2 ---
// 128x128x64 tiles (bf16), 37 KB LDS, 4 blocks/CU. Dense modulo enumeration.
__global__ __launch_bounds__(256) void moe_gemm2(
    const u16* __restrict__ act, const u16* __restrict__ w2c,
    const u32* __restrict__ pairs, const float* __restrict__ wslot,
    const int* __restrict__ counts,
    u16* __restrict__ eout, float* __restrict__ out, int useEout, int T)
{
    const int ytile = blockIdx.y;                    // 0..271
    const int e     = ytile % (NEXP + 1);            // expert fastest
    const int ti    = ytile / (NEXP + 1);
    const int r0    = ti << 7;
    const int n0    = blockIdx.x * 128;
    const int cnt = (e == NEXP) ? T : min(max(counts[e], 0), T);
    if (r0 >= cnt) return;
    const int nv = min(128, cnt - r0);

    const u16* W2 = w2c + (size_t)e * DIM * HID;

    __shared__ __align__(16) u16 sA[128 * PITCH];
    __shared__ __align__(16) u16 sB[128 * PITCH];
    __shared__ u32 sEnt[128];

    const int tid = threadIdx.x;
    if (tid < 128) {
        u32 ent = (tid < nv) ? pairs[(size_t)e * T + r0 + tid] : 0u;
        u32 tk = ent >> 3, sl = ent & 7u;
        if (tk >= (u32)T) tk = 0;
        if (sl >= SLOTS)  sl = 0;
        sEnt[tid] = (tk << 3) | sl;
    }
    __syncthreads();

    const int ar = tid >> 1;
    const int ac = (tid & 1) * 32;
    const u32 entA = sEnt[ar];
    const u16* arow = act + ((size_t)(entA >> 3) * SLOTS + (entA & 7u)) * HID;
    const u16* brow = W2 + (size_t)(n0 + ar) * HID;

    const int wv   = tid >> 6;
    const int lane = tid & 63;
    const int l15  = lane & 15;
    const int kq   = (lane >> 4) * 8;
    const int m0   = (wv & 1) * 64;     // wave 2x2 grid over 128x128
    const int nc0  = (wv >> 1) * 64;

    f32x4 acc[4][4];
#pragma unroll
    for (int i = 0; i < 4; ++i)
#pragma unroll
        for (int j = 0; j < 4; ++j) acc[i][j] = (f32x4){0,0,0,0};

    for (int kt = 0; kt < HID; kt += 64) {
        __syncthreads();
        *(uint4*)&sA[ar*PITCH + ac]      = *(const uint4*)&arow[kt + ac];
        *(uint4*)&sA[ar*PITCH + ac +  8] = *(const uint4*)&arow[kt + ac +  8];
        *(uint4*)&sA[ar*PITCH + ac + 16] = *(const uint4*)&arow[kt + ac + 16];
        *(uint4*)&sA[ar*PITCH + ac + 24] = *(const uint4*)&arow[kt + ac + 24];
        *(uint4*)&sB[ar*PITCH + ac]      = *(const uint4*)&brow[kt + ac];
        *(uint4*)&sB[ar*PITCH + ac +  8] = *(const uint4*)&brow[kt + ac +  8];
        *(uint4*)&sB[ar*PITCH + ac + 16] = *(const uint4*)&brow[kt + ac + 16];
        *(uint4*)&sB[ar*PITCH + ac + 24] = *(const uint4*)&brow[kt + ac + 24];
        __syncthreads();
#pragma unroll
        for (int ks = 0; ks < 64; ks += 32) {
            bf16x8 af[4], bf[4];
#pragma unroll
            for (int mf = 0; mf < 4; ++mf)
                af[mf] = *(const bf16x8*)&sA[(m0 + mf*16 + l15)*PITCH + ks + kq];
#pragma unroll
            for (int nf = 0; nf < 4; ++nf)
                bf[nf] = *(const bf16x8*)&sB[(nc0 + nf*16 + l15)*PITCH + ks + kq];
#pragma unroll
            for (int mf = 0; mf < 4; ++mf)
#pragma unroll
                for (int nf = 0; nf < 4; ++nf)
                    acc[mf][nf] = __builtin_amdgcn_mfma_f32_16x16x32_bf16(af[mf], bf[nf], acc[mf][nf], 0, 0, 0);
        }
    }
#pragma unroll
    for (int mf = 0; mf < 4; ++mf)
#pragma unroll
    for (int nf = 0; nf < 4; ++nf)
#pragma unroll
    for (int r = 0; r < 4; ++r) {
        int ml = m0 + mf*16 + (lane >> 4)*4 + r;
        if (ml < nv) {
            u32 ent = sEnt[ml];
            u32 tk = ent >> 3;
            float cw = wslot[tk * SLOTS + (ent & 7u)];
            int col = n0 + nc0 + nf*16 + l15;
            float v = cw * acc[mf][nf][r];
            if (useEout) {
                size_t sidx = (size_t)tk * SLOTS + (ent & 7u);
                eout[sidx * DIM + col] = f2bf(v);
            } else {
                atomicAdd(&out[(size_t)tk * DIM + col], v);
            }
        }
    }
}

// ---------------------------------------------------------------- combine ---
__global__ __launch_bounds__(256) void moe_combine(
    const u16* __restrict__ eout, float* __restrict__ out, int n4)
{
    int i = blockIdx.x * 256 + threadIdx.x;
    if (i >= n4) return;
    int o4 = i * 4;
    int t = o4 >> 10;                   // DIM = 1024
    int col = o4 & 1023;
    float a0 = 0.f, a1 = 0.f, a2 = 0.f, a3 = 0.f;
#pragma unroll
    for (int s = 0; s < SLOTS; ++s) {
        const u16* row = eout + ((size_t)t * SLOTS + s) * DIM + col;
        ushort4 u = *(const ushort4*)row;
        a0 += bf2f(u.x); a1 += bf2f(u.y); a2 += bf2f(u.z); a3 += bf2f(u.w);
    }
    float4* op = (float4*)(out + (size_t)t * DIM + col);
    *op = (float4){a0, a1, a2, a3};
}

// ------------------------------------------------------------------ launch --
extern "C" void kernel_launch(void* const* d_in, const int* in_sizes, int n_in,
                              void* d_out, int out_size, void* d_ws, size_t ws_size,
                              hipStream_t stream)
{
    (void)n_in; (void)out_size;
    const float* x    = (const float*)d_in[0];
    const float* gate = (const float*)d_in[1];
    const float* w1   = (const float*)d_in[2];
    const float* w3   = (const float*)d_in[3];
    const float* w2   = (const float*)d_in[4];
    const float* sw1  = (const float*)d_in[5];
    const float* sw3  = (const float*)d_in[6];
    const float* sw2  = (const float*)d_in[7];
    float* out = (float*)d_out;
    const int T = in_sizes[0] / DIM;     // 2048

    char* w = (char*)d_ws;
    int*  counts = (int*)(w);            // 256 B zeroed each call
    size_t off = 4096;
    u32*   pairs = (u32*)(w + off);  off += (size_t)(NEXP + 1) * T * 4;   // 139 KB
    float* wslot = (float*)(w + off); off += (size_t)T * SLOTS * 4;       //  40 KB
    off = (off + 255) & ~(size_t)255;
    u16*   actb  = (u16*)(w + off);  off += (size_t)T * SLOTS * HID * 2;  // 10.5 MB
    off = (off + 255) & ~(size_t)255;
    u16*   cvtb  = (u16*)(w + off);
    const size_t xChunks = (size_t)T * DIM / 8;
    const size_t cvtChunks = SEG_B5 + xChunks;                            // 3,604,480
    off += cvtChunks * 8 * 2;                                             // 57.7 MB
    off = (off + 255) & ~(size_t)255;
    u16*   eoutb = (u16*)(w + off);
    const size_t needEout = off + (size_t)T * SLOTS * DIM * 2;            // ~89.4 MB

    u16* W1c = cvtb;                       // [17][HID][DIM] (sw1 = expert 16)
    u16* W3c = cvtb + SEG_B1 * 8;
    u16* W2c = cvtb + SEG_B3 * 8;
    u16* xb  = cvtb + SEG_B5 * 8;

    const int useEout = (ws_size >= needEout) ? 1 : 0;   // constant -> graph-safe

    hipMemsetAsync(w, 0, 256, stream);                   // counts
    if (!useEout)
        hipMemsetAsync(out, 0, (size_t)T * DIM * sizeof(float), stream);

    const int nCvt = (int)((cvtChunks + 511) / 512);     // 2 chunks / thread
    moe_prep<<<T + nCvt, 256, 0, stream>>>(
        x, gate, w1, w3, w2, sw1, sw3, sw2, cvtb, counts, pairs, wslot, T);

    moe_gemm1<<<dim3(HID / 64, (NEXP + 1) * TPE), 256, 0, stream>>>(
        xb, W1c, W3c, pairs, counts, actb, T);
    moe_gemm2<<<dim3(DIM / 128, (NEXP + 1) * TPE), 256, 0, stream>>>(
        actb, W2c, pairs, wslot, counts, eoutb, out, useEout, T);
    if (useEout)
        moe_combine<<<(T * DIM / 4 + 255) / 256, 256, 0, stream>>>(
            eoutb, out, T * DIM / 4);
}